// Round 1
// baseline (140.047 us; speedup 1.0000x reference)
//
#include <hip/hip_runtime.h>
#include <hip/hip_bf16.h>
#include <stdint.h>

// Problem shape (fixed by reference)
#define B_ 32
#define T_ 1024
#define J_ 256
#define D_ 512

typedef __attribute__((ext_vector_type(8))) short short8;   // 8 bf16 (4 VGPRs)
typedef __attribute__((ext_vector_type(4))) float floatx4;  // MFMA C/D frag

// ---------------------------------------------------------------------------
// Kernel 1: prep — cast h*w_m -> bf16 A, u -> bf16 Bu, and compute the rank-1
// terms term_h[b,t] = h.w_h, term_u[b,j] = u.w_u in fp32.
// One wave (64 lanes) per row of 512; each lane handles 8 contiguous floats.
// ---------------------------------------------------------------------------
__global__ __launch_bounds__(256) void prep_kernel(
    const float* __restrict__ h, const float* __restrict__ u,
    const float* __restrict__ w,
    __hip_bfloat16* __restrict__ A, __hip_bfloat16* __restrict__ Bu,
    float* __restrict__ th, float* __restrict__ tu)
{
    int row  = blockIdx.x * 4 + (threadIdx.x >> 6);   // one wave per row
    int lane = threadIdx.x & 63;
    const float* src;
    const float* wsum;   // weight for the scalar (dot) term
    const float* wmul;   // weight multiplied into the bf16 matrix (h only)
    __hip_bfloat16* dst;
    float* tdst;
    if (row < B_ * T_) {                 // h row  (branch is wave-uniform)
        src  = h + (size_t)row * D_;
        wsum = w;                        // w_h = w[0:512]
        wmul = w + 2 * D_;               // w_m = w[1024:1536]
        dst  = A + (size_t)row * D_;
        tdst = th + row;
    } else {                             // u row
        int r = row - B_ * T_;
        src  = u + (size_t)r * D_;
        wsum = w + D_;                   // w_u = w[512:1024]
        wmul = nullptr;
        dst  = Bu + (size_t)r * D_;
        tdst = tu + r;
    }
    int base = lane * 8;
    float4 v0  = *(const float4*)(src  + base);
    float4 v1  = *(const float4*)(src  + base + 4);
    float4 ws0 = *(const float4*)(wsum + base);
    float4 ws1 = *(const float4*)(wsum + base + 4);
    float s = v0.x*ws0.x + v0.y*ws0.y + v0.z*ws0.z + v0.w*ws0.w
            + v1.x*ws1.x + v1.y*ws1.y + v1.z*ws1.z + v1.w*ws1.w;

    float vals[8] = {v0.x, v0.y, v0.z, v0.w, v1.x, v1.y, v1.z, v1.w};
    if (wmul) {
        float4 m0 = *(const float4*)(wmul + base);
        float4 m1 = *(const float4*)(wmul + base + 4);
        vals[0]*=m0.x; vals[1]*=m0.y; vals[2]*=m0.z; vals[3]*=m0.w;
        vals[4]*=m1.x; vals[5]*=m1.y; vals[6]*=m1.z; vals[7]*=m1.w;
    }
    union { __hip_bfloat16 b[8]; uint4 q; } pk;
#pragma unroll
    for (int i = 0; i < 8; i++) pk.b[i] = __float2bfloat16(vals[i]);
    *(uint4*)(dst + base) = pk.q;        // 16B coalesced bf16 store

    // wave-64 shuffle reduction for the dot term
#pragma unroll
    for (int off = 32; off > 0; off >>= 1) s += __shfl_down(s, off, 64);
    if (lane == 0) *tdst = s;
}

// ---------------------------------------------------------------------------
// Kernel 2: batched GEMM C[b] = A[b] @ Bu[b]^T  (+ term_h + term_u epilogue)
// m97-style: 128x128 tile, BK=32, 4 waves in 2x2, each wave 4x4 of
// 16x16x32 bf16 MFMA, global_load_lds width-16 staging.
// ---------------------------------------------------------------------------
__device__ inline void gload_lds16(const void* g, void* l) {
    __builtin_amdgcn_global_load_lds(
        (__attribute__((address_space(1))) void*)(g),
        (__attribute__((address_space(3))) void*)(l),
        16, 0, 0);
}

__global__ __launch_bounds__(256) void gemm_kernel(
    const __hip_bfloat16* __restrict__ A,   // [B, T, D] bf16 (= h*w_m)
    const __hip_bfloat16* __restrict__ Bu,  // [B, J, D] bf16 (= u)
    const float* __restrict__ th,           // [B*T]
    const float* __restrict__ tu,           // [B*J]
    float* __restrict__ out)                // [B, T, J] fp32
{
    __shared__ __align__(16) __hip_bfloat16 sA[128 * 32];
    __shared__ __align__(16) __hip_bfloat16 sB[128 * 32];

    const int b   = blockIdx.y;
    const int tM  = blockIdx.x >> 1;        // T/128 = 8 tiles
    const int tN  = blockIdx.x & 1;         // J/128 = 2 tiles
    const int tid = threadIdx.x;
    const int w = tid >> 6, lane = tid & 63;
    const int wr = w >> 1, wc = w & 1;      // 2x2 wave grid, 64x64 each

    const __hip_bfloat16* Ab = A  + ((size_t)b * T_ + tM * 128) * D_;
    const __hip_bfloat16* Bb = Bu + ((size_t)b * J_ + tN * 128) * D_;

    // staging: thread t covers tile elements [t*8, t*8+8) -> row t/4, col (t%4)*8
    const int sr = tid >> 2;                // 0..63 (issue 0); +64 for issue 1
    const int sc = (tid & 3) * 8;
    const int ldsOff = tid * 8;             // element offset == sr*32+sc (wave-linear!)

    floatx4 acc[4][4];
#pragma unroll
    for (int i = 0; i < 4; i++)
#pragma unroll
        for (int j = 0; j < 4; j++) acc[i][j] = (floatx4)0.0f;

    const int kb = (lane >> 4) * 8;         // k-offset of this lane's frag
    const int fr = lane & 15;               // m (or n) within the 16-tile

    for (int k0 = 0; k0 < D_; k0 += 32) {
        gload_lds16(Ab + (size_t)sr        * D_ + k0 + sc, sA + ldsOff);
        gload_lds16(Ab + (size_t)(sr + 64) * D_ + k0 + sc, sA + 64 * 32 + ldsOff);
        gload_lds16(Bb + (size_t)sr        * D_ + k0 + sc, sB + ldsOff);
        gload_lds16(Bb + (size_t)(sr + 64) * D_ + k0 + sc, sB + 64 * 32 + ldsOff);
        __syncthreads();   // drains vmcnt (global_load_lds) before use

        short8 af[4], bfr[4];
#pragma unroll
        for (int mi = 0; mi < 4; mi++)
            af[mi] = *(const short8*)(sA + (wr * 64 + mi * 16 + fr) * 32 + kb);
#pragma unroll
        for (int ni = 0; ni < 4; ni++)
            bfr[ni] = *(const short8*)(sB + (wc * 64 + ni * 16 + fr) * 32 + kb);
#pragma unroll
        for (int mi = 0; mi < 4; mi++)
#pragma unroll
            for (int ni = 0; ni < 4; ni++)
                acc[mi][ni] = __builtin_amdgcn_mfma_f32_16x16x32_bf16(
                    af[mi], bfr[ni], acc[mi][ni], 0, 0, 0);
        __syncthreads();
    }

    // epilogue: C/D layout col = lane&15, row = (lane>>4)*4 + reg  [m89/m91]
    const size_t outB = (size_t)b * T_ * J_;
    const int colq = lane & 15;
    const int rq   = (lane >> 4) * 4;
    const float* thb = th + b * T_;
    const float* tub = tu + b * J_;
#pragma unroll
    for (int mi = 0; mi < 4; mi++) {
        int r0 = tM * 128 + wr * 64 + mi * 16 + rq;
#pragma unroll
        for (int ni = 0; ni < 4; ni++) {
            int col = tN * 128 + wc * 64 + ni * 16 + colq;
            float tuv = tub[col];
#pragma unroll
            for (int r = 0; r < 4; r++) {
                out[outB + (size_t)(r0 + r) * J_ + col] =
                    acc[mi][ni][r] + thb[r0 + r] + tuv;
            }
        }
    }
}

// ---------------------------------------------------------------------------
extern "C" void kernel_launch(void* const* d_in, const int* in_sizes, int n_in,
                              void* d_out, int out_size, void* d_ws, size_t ws_size,
                              hipStream_t stream)
{
    const float* h = (const float*)d_in[0];
    const float* u = (const float*)d_in[1];
    const float* w = (const float*)d_in[2];
    float* out = (float*)d_out;

    uint8_t* ws = (uint8_t*)d_ws;
    __hip_bfloat16* A  = (__hip_bfloat16*)ws;                              // 32 MiB
    __hip_bfloat16* Bu = (__hip_bfloat16*)(ws + (size_t)B_*T_*D_*2);       //  8 MiB
    float* th = (float*)(ws + (size_t)B_*T_*D_*2 + (size_t)B_*J_*D_*2);    // 128 KiB
    float* tu = th + B_*T_;                                                //  32 KiB

    // one wave per row; 4 rows per 256-thread block
    prep_kernel<<<dim3((B_*T_ + B_*J_) / 4), 256, 0, stream>>>(h, u, w, A, Bu, th, tu);

    // 128x128 output tiles: (T/128)*(J/128)=16 tiles/batch, 32 batches
    gemm_kernel<<<dim3((T_/128)*(J_/128), B_), 256, 0, stream>>>(A, Bu, th, tu, out);
}

// Round 2
// 136.630 us; speedup vs baseline: 1.0250x; 1.0250x over previous
//
#include <hip/hip_runtime.h>
#include <hip/hip_bf16.h>
#include <stdint.h>

// Problem shape (fixed by reference)
#define B_ 32
#define T_ 1024
#define J_ 256
#define D_ 512

typedef __attribute__((ext_vector_type(8))) short short8;   // 8 bf16 (4 VGPRs)
typedef __attribute__((ext_vector_type(4))) float floatx4;  // MFMA C/D frag

// ---------------------------------------------------------------------------
// Kernel 1: prep_u — B2[j,k] = bf16(u[j,k]*w_m[k] + w_h[k]),
//                    tu[j]   = sum_k u[j,k]*w_u[k]   (fp32)
// Identity: out[t,j] = sum_k h[t,k]*B2[j,k] + tu[j]
//   (term_h folds into the GEMM because sum_k h*w_h rides along in B2)
// One wave per row of 512; each lane handles 8 contiguous floats.
// Traffic: read u 16 MiB + w, write 8 MiB bf16 + 32 KiB  ->  ~4 us
// ---------------------------------------------------------------------------
__global__ __launch_bounds__(256) void prep_u_kernel(
    const float* __restrict__ u, const float* __restrict__ w,
    __hip_bfloat16* __restrict__ B2, float* __restrict__ tu)
{
    int row  = blockIdx.x * 4 + (threadIdx.x >> 6);   // one wave per u-row
    int lane = threadIdx.x & 63;
    const float* src = u + (size_t)row * D_;
    int base = lane * 8;

    float4 v0  = *(const float4*)(src + base);
    float4 v1  = *(const float4*)(src + base + 4);
    float4 wh0 = *(const float4*)(w + base);            // w_h = w[0:512]
    float4 wh1 = *(const float4*)(w + base + 4);
    float4 wu0 = *(const float4*)(w + D_ + base);       // w_u = w[512:1024]
    float4 wu1 = *(const float4*)(w + D_ + base + 4);
    float4 wm0 = *(const float4*)(w + 2*D_ + base);     // w_m = w[1024:1536]
    float4 wm1 = *(const float4*)(w + 2*D_ + base + 4);

    float s = v0.x*wu0.x + v0.y*wu0.y + v0.z*wu0.z + v0.w*wu0.w
            + v1.x*wu1.x + v1.y*wu1.y + v1.z*wu1.z + v1.w*wu1.w;

    float vals[8] = {
        v0.x*wm0.x + wh0.x, v0.y*wm0.y + wh0.y,
        v0.z*wm0.z + wh0.z, v0.w*wm0.w + wh0.w,
        v1.x*wm1.x + wh1.x, v1.y*wm1.y + wh1.y,
        v1.z*wm1.z + wh1.z, v1.w*wm1.w + wh1.w };

    union { __hip_bfloat16 b[8]; uint4 q; } pk;
#pragma unroll
    for (int i = 0; i < 8; i++) pk.b[i] = __float2bfloat16(vals[i]);
    *(uint4*)(B2 + (size_t)row * D_ + base) = pk.q;     // 16B coalesced store

#pragma unroll
    for (int off = 32; off > 0; off >>= 1) s += __shfl_down(s, off, 64);
    if (lane == 0) tu[row] = s;
}

// ---------------------------------------------------------------------------
// Kernel 2: fused GEMM  out[b] = bf16(h[b]) @ B2[b]^T + tu
// 128x128 tile, BK=32, 4 waves in 2x2, each wave 4x4 of 16x16x32 bf16 MFMA.
// A (= h) is read as fp32 from global, cast to bf16 in registers, staged to
// LDS via ds_write_b128.  B2 (bf16) staged via global_load_lds width-16.
// No bf16 A materialization in HBM: saves the 32 MiB write + 32 MiB read.
// ---------------------------------------------------------------------------
__device__ inline void gload_lds16(const void* g, void* l) {
    __builtin_amdgcn_global_load_lds(
        (__attribute__((address_space(1))) void*)(g),
        (__attribute__((address_space(3))) void*)(l),
        16, 0, 0);
}

__global__ __launch_bounds__(256) void gemm_kernel(
    const float* __restrict__ h,            // [B, T, D] fp32
    const __hip_bfloat16* __restrict__ B2,  // [B, J, D] bf16 (= u*w_m + w_h)
    const float* __restrict__ tu,           // [B*J] fp32
    float* __restrict__ out)                // [B, T, J] fp32
{
    __shared__ __align__(16) __hip_bfloat16 sA[128 * 32];
    __shared__ __align__(16) __hip_bfloat16 sB[128 * 32];

    const int b   = blockIdx.y;
    const int tM  = blockIdx.x >> 1;        // T/128 = 8 tiles
    const int tN  = blockIdx.x & 1;         // J/128 = 2 tiles
    const int tid = threadIdx.x;
    const int w = tid >> 6, lane = tid & 63;
    const int wr = w >> 1, wc = w & 1;      // 2x2 wave grid, 64x64 each

    const float*          Ah = h  + ((size_t)b * T_ + tM * 128) * D_;
    const __hip_bfloat16* Bb = B2 + ((size_t)b * J_ + tN * 128) * D_;

    // B staging (global_load_lds): thread t -> row t/4, col (t%4)*8; two issues
    const int sr = tid >> 2;
    const int sc = (tid & 3) * 8;
    const int ldsOffB = tid * 8;            // == sr*32+sc (wave-linear, required)

    // A staging (register cast): thread t -> row t/2, cols (t%2)*16 .. +16
    const int ar = tid >> 1;                // 0..127
    const int ac = (tid & 1) * 16;

    floatx4 acc[4][4];
#pragma unroll
    for (int i = 0; i < 4; i++)
#pragma unroll
        for (int j = 0; j < 4; j++) acc[i][j] = (floatx4)0.0f;

    const int kb = (lane >> 4) * 8;         // k-offset of this lane's frag
    const int fr = lane & 15;               // m (or n) within the 16-tile

    for (int k0 = 0; k0 < D_; k0 += 32) {
        // async bf16 B staging (in flight while we cast A)
        gload_lds16(Bb + (size_t)sr        * D_ + k0 + sc, sB + ldsOffB);
        gload_lds16(Bb + (size_t)(sr + 64) * D_ + k0 + sc, sB + 64 * 32 + ldsOffB);

        // A: load 16 fp32, cast to bf16, stage 32B to LDS
        {
            const float* ap = Ah + (size_t)ar * D_ + k0 + ac;
            float4 a0 = *(const float4*)(ap);
            float4 a1 = *(const float4*)(ap + 4);
            float4 a2 = *(const float4*)(ap + 8);
            float4 a3 = *(const float4*)(ap + 12);
            union { __hip_bfloat16 b[16]; uint4 q[2]; } pk;
            pk.b[0]=__float2bfloat16(a0.x); pk.b[1]=__float2bfloat16(a0.y);
            pk.b[2]=__float2bfloat16(a0.z); pk.b[3]=__float2bfloat16(a0.w);
            pk.b[4]=__float2bfloat16(a1.x); pk.b[5]=__float2bfloat16(a1.y);
            pk.b[6]=__float2bfloat16(a1.z); pk.b[7]=__float2bfloat16(a1.w);
            pk.b[8]=__float2bfloat16(a2.x); pk.b[9]=__float2bfloat16(a2.y);
            pk.b[10]=__float2bfloat16(a2.z); pk.b[11]=__float2bfloat16(a2.w);
            pk.b[12]=__float2bfloat16(a3.x); pk.b[13]=__float2bfloat16(a3.y);
            pk.b[14]=__float2bfloat16(a3.z); pk.b[15]=__float2bfloat16(a3.w);
            uint4* dst = (uint4*)(sA + ar * 32 + ac);
            dst[0] = pk.q[0];
            dst[1] = pk.q[1];
        }
        __syncthreads();   // drains vmcnt (global_load_lds) + lgkm (ds_write)

        short8 af[4], bfr[4];
#pragma unroll
        for (int mi = 0; mi < 4; mi++)
            af[mi] = *(const short8*)(sA + (wr * 64 + mi * 16 + fr) * 32 + kb);
#pragma unroll
        for (int ni = 0; ni < 4; ni++)
            bfr[ni] = *(const short8*)(sB + (wc * 64 + ni * 16 + fr) * 32 + kb);
#pragma unroll
        for (int mi = 0; mi < 4; mi++)
#pragma unroll
            for (int ni = 0; ni < 4; ni++)
                acc[mi][ni] = __builtin_amdgcn_mfma_f32_16x16x32_bf16(
                    af[mi], bfr[ni], acc[mi][ni], 0, 0, 0);
        __syncthreads();
    }

    // epilogue: C/D layout col = lane&15, row = (lane>>4)*4 + reg  [m89/m91]
    const size_t outB = (size_t)b * T_ * J_;
    const int colq = lane & 15;
    const int rq   = (lane >> 4) * 4;
    const float* tub = tu + b * J_;
#pragma unroll
    for (int mi = 0; mi < 4; mi++) {
        int r0 = tM * 128 + wr * 64 + mi * 16 + rq;
#pragma unroll
        for (int ni = 0; ni < 4; ni++) {
            int col = tN * 128 + wc * 64 + ni * 16 + colq;
            float tuv = tub[col];
#pragma unroll
            for (int r = 0; r < 4; r++) {
                out[outB + (size_t)(r0 + r) * J_ + col] =
                    acc[mi][ni][r] + tuv;
            }
        }
    }
}

// ---------------------------------------------------------------------------
extern "C" void kernel_launch(void* const* d_in, const int* in_sizes, int n_in,
                              void* d_out, int out_size, void* d_ws, size_t ws_size,
                              hipStream_t stream)
{
    const float* h = (const float*)d_in[0];
    const float* u = (const float*)d_in[1];
    const float* w = (const float*)d_in[2];
    float* out = (float*)d_out;

    uint8_t* ws = (uint8_t*)d_ws;
    __hip_bfloat16* B2 = (__hip_bfloat16*)ws;                 // 8 MiB
    float* tu = (float*)(ws + (size_t)B_ * J_ * D_ * 2);      // 32 KiB

    // one wave per u-row; 4 rows per 256-thread block; 8192 rows total
    prep_u_kernel<<<dim3(B_ * J_ / 4), 256, 0, stream>>>(u, w, B2, tu);

    // 128x128 output tiles: (T/128)*(J/128)=16 tiles/batch, 32 batches
    gemm_kernel<<<dim3((T_ / 128) * (J_ / 128), B_), 256, 0, stream>>>(h, B2, tu, out);
}